// Round 1
// baseline (193.664 us; speedup 1.0000x reference)
//
#include <hip/hip_runtime.h>

#define N_PTS 128
#define EPS_F 1e-10f
#define FAR_F 1e10f
#define RAYS_PER_BLOCK 8   // 4 waves/block x 2 rays/wave
#define MAX_GRID 2048

// DPP ctrl encodings (gfx9/CDNA):
//   ROW_SHR1=0x111 SHR2=0x112 SHR4=0x114 SHR8=0x118
//   ROW_BCAST15=0x142 ROW_BCAST31=0x143
//   WAVE_SHL1=0x130 (lane i <- i+1)   WAVE_SHR1=0x138 (lane i <- i-1)
template<int CTRL, int ROW_MASK>
__device__ __forceinline__ float dpp_mov(float src, float old) {
    union { float f; int i; } s, o, r;
    s.f = src; o.f = old;
    r.i = __builtin_amdgcn_update_dpp(o.i, s.i, CTRL, ROW_MASK, 0xF, false);
    return r.f;
}

// 32-lane (half-wave) sum; totals land in lane 31 (half A) and lane 63 (half B).
__device__ __forceinline__ float half32_reduce_add(float x) {
    x += dpp_mov<0x111, 0xF>(x, 0.0f);
    x += dpp_mov<0x112, 0xF>(x, 0.0f);
    x += dpp_mov<0x114, 0xF>(x, 0.0f);
    x += dpp_mov<0x118, 0xF>(x, 0.0f);
    x += dpp_mov<0x142, 0xA>(x, 0.0f);  // row1 += lane15 (row0 tot), row3 += lane47 (row2 tot)
    return x;
}

// One wave = 2 rays (lanes 0-31 ray A, lanes 32-63 ray B); lane owns points 4s..4s+3.
// All global loads are 16B-aligned dwordx4. Persistent blocks with register
// double-buffer prefetch; outputs staged in LDS and stored block-coalesced.
__global__ __launch_bounds__(256) void volrend_kernel(
        const float* __restrict__ density,
        const float* __restrict__ feature,
        const float* __restrict__ depth,
        float* __restrict__ out, int n_rays, int iters) {
    const int lane = threadIdx.x & 63;
    const int sub  = lane & 31;          // lane within the 32-lane half
    const int h    = lane >> 5;          // which ray of the pair
    const int wid  = threadIdx.x >> 6;   // wave id within block
    const int stride8 = gridDim.x * RAYS_PER_BLOCK;

    __shared__ float sbuf[2][64];        // [0..23]=rgb of 8 rays, [32..55]=depth

    int base8 = blockIdx.x * RAYS_PER_BLOCK;

    // Prefetch iteration 0 (5 x global_load_dwordx4, 80 B/lane, 5120 B/wave).
    {
        const int ray = base8 + (wid << 1) + h;
        const size_t dz = (size_t)ray * N_PTS + (sub << 2);
        // fallthrough into loop-carried regs below
        // (declared outside the block)
    }
    int ray0 = base8 + (wid << 1) + h;
    size_t dz0 = (size_t)ray0 * N_PTS + (sub << 2);
    float4 dns = *(const float4*)(density + dz0);
    float4 zz  = *(const float4*)(depth   + dz0);
    const float4* fp0 = (const float4*)(feature + (size_t)ray0 * (N_PTS * 3) + sub * 12);
    float4 fa = fp0[0], fb = fp0[1], fc = fp0[2];

    for (int it = 0; it < iters; ++it) {
        const bool more = (it + 1) < iters;
        float4 ndns, nzz, nfa, nfb, nfc;
        if (more) {  // issue next ray-pair's loads before touching current data
            const int nray = base8 + stride8 + (wid << 1) + h;
            const size_t ndz = (size_t)nray * N_PTS + (sub << 2);
            ndns = *(const float4*)(density + ndz);
            nzz  = *(const float4*)(depth   + ndz);
            const float4* nfp = (const float4*)(feature + (size_t)nray * (N_PTS * 3) + sub * 12);
            nfa = nfp[0]; nfb = nfp[1]; nfc = nfp[2];
        }

        // deltas: z4 = next lane's z0 (lane 31/63 -> FAR overrides)
        float nz = dpp_mov<0x130, 0xF>(zz.x, 0.0f);   // wave_shl1
        float d0 = zz.y - zz.x;
        float d1 = zz.z - zz.y;
        float d2 = zz.w - zz.z;
        float d3 = (sub == 31) ? FAR_F : (nz - zz.w);

        float e0 = __expf(-d0 * dns.x);
        float e1 = __expf(-d1 * dns.y);
        float e2 = __expf(-d2 * dns.z);
        float e3 = __expf(-d3 * dns.w);
        float a0 = 1.0f - e0, a1 = 1.0f - e1, a2 = 1.0f - e2, a3 = 1.0f - e3;
        float f0 = e0 + EPS_F, f1 = e1 + EPS_F, f2 = e2 + EPS_F, f3 = e3 + EPS_F;

        // local prefix products, then 32-lane inclusive product scan of P
        float f01  = f0 * f1;
        float f012 = f01 * f2;
        float p    = f012 * f3;
        p *= dpp_mov<0x111, 0xF>(p, 1.0f);   // row_shr:1
        p *= dpp_mov<0x112, 0xF>(p, 1.0f);   // row_shr:2
        p *= dpp_mov<0x114, 0xF>(p, 1.0f);   // row_shr:4
        p *= dpp_mov<0x118, 0xF>(p, 1.0f);   // row_shr:8
        p *= dpp_mov<0x142, 0xA>(p, 1.0f);   // row1 *= lane15, row3 *= lane47
        // exclusive: T entering this lane's first point; lanes 0 and 32 -> 1.0
        float Ts = dpp_mov<0x138, 0xF>(p, 1.0f);   // wave_shr:1 (lane0 keeps old=1)
        if (sub == 0) Ts = 1.0f;                   // lane 32 got lane31's value

        float w0 = Ts   * a0;
        float T1 = Ts   * f0;   float w1 = T1 * a1;
        float T2 = Ts   * f01;  float w2 = T2 * a2;
        float T3 = Ts   * f012; float w3 = T3 * a3;

        // feature unpack: fa=(p0x,p0y,p0z,p1x) fb=(p1y,p1z,p2x,p2y) fc=(p2z,p3x,p3y,p3z)
        float rx = half32_reduce_add(w0 * fa.x + w1 * fa.w + w2 * fb.z + w3 * fc.y);
        float ry = half32_reduce_add(w0 * fa.y + w1 * fb.x + w2 * fb.w + w3 * fc.z);
        float rz = half32_reduce_add(w0 * fa.z + w1 * fb.y + w2 * fc.x + w3 * fc.w);
        float dd = half32_reduce_add(w0 * zz.x + w1 * zz.y + w2 * zz.z + w3 * zz.w);

        const int b = it & 1;
        if (sub == 31) {                    // lanes 31 (ray A) and 63 (ray B)
            const int r8 = (wid << 1) + h;  // ray index within block [0,8)
            sbuf[b][r8 * 3 + 0] = rx;
            sbuf[b][r8 * 3 + 1] = ry;
            sbuf[b][r8 * 3 + 2] = rz;
            sbuf[b][32 + r8 * 3 + 0] = dd;
            sbuf[b][32 + r8 * 3 + 1] = dd;
            sbuf[b][32 + r8 * 3 + 2] = dd;
        }
        __syncthreads();
        {
            const int t = threadIdx.x;
            float* orgb = out + (size_t)base8 * 3;
            float* odep = out + (size_t)n_rays * 3 + (size_t)base8 * 3;
            if (t < 24)                     orgb[t]      = sbuf[b][t];
            else if (t >= 32 && t < 56)     odep[t - 32] = sbuf[b][t];
        }
        // double-buffered LDS + one barrier/iter => no second barrier needed

        if (more) { dns = ndns; zz = nzz; fa = nfa; fb = nfb; fc = nfc; }
        base8 += stride8;
    }
}

extern "C" void kernel_launch(void* const* d_in, const int* in_sizes, int n_in,
                              void* d_out, int out_size, void* d_ws, size_t ws_size,
                              hipStream_t stream) {
    const float* density = (const float*)d_in[0];
    const float* feature = (const float*)d_in[1];
    const float* depth   = (const float*)d_in[2];
    float* out = (float*)d_out;
    const int n_rays = in_sizes[0] / N_PTS;       // 65536
    int nblk8 = n_rays / RAYS_PER_BLOCK;          // 8192 block-iterations
    int grid = nblk8 < MAX_GRID ? nblk8 : MAX_GRID;
    while (grid > 1 && (nblk8 % grid)) --grid;    // keep iters exact
    const int iters = nblk8 / grid;               // 4 for the bench shape
    volrend_kernel<<<grid, 256, 0, stream>>>(density, feature, depth, out,
                                             n_rays, iters);
}

// Round 3
// 192.381 us; speedup vs baseline: 1.0067x; 1.0067x over previous
//
#include <hip/hip_runtime.h>

#define N_PTS 128
#define EPS_F 1e-10f
#define FAR_F 1e10f
#define MAX_GRID 2048

// DPP ctrl encodings (gfx9/CDNA):
//   ROW_SHR1=0x111 SHR2=0x112 SHR4=0x114 SHR8=0x118
//   ROW_BCAST15=0x142 ROW_BCAST31=0x143
//   WAVE_SHL1=0x130 (lane i <- i+1)   WAVE_SHR1=0x138 (lane i <- i-1)
template<int CTRL, int ROW_MASK>
__device__ __forceinline__ float dpp_mov(float src, float old) {
    union { float f; int i; } s, o, r;
    s.f = src; o.f = old;
    r.i = __builtin_amdgcn_update_dpp(o.i, s.i, CTRL, ROW_MASK, 0xF, false);
    return r.f;
}

// 32-lane (half-wave) sum; totals land in lane 31 (half A) and lane 63 (half B).
__device__ __forceinline__ float half32_reduce_add(float x) {
    x += dpp_mov<0x111, 0xF>(x, 0.0f);
    x += dpp_mov<0x112, 0xF>(x, 0.0f);
    x += dpp_mov<0x114, 0xF>(x, 0.0f);
    x += dpp_mov<0x118, 0xF>(x, 0.0f);
    x += dpp_mov<0x142, 0xA>(x, 0.0f);  // row1 += lane15 tot, row3 += lane47 tot
    return x;
}

// Compute + reduce + store for one ray-pair held in registers.
// lanes 0-31 = ray A, lanes 32-63 = ray B; lane owns points 4*sub .. 4*sub+3.
__device__ __forceinline__ void process_pair(
        const float4& dns, const float4& zz,
        const float4& fa, const float4& fb, const float4& fc,
        int sub, int ray, int n_rays, float* __restrict__ out) {
    // deltas: next lane's z0 via wave_shl1; lanes 31/63 overridden with FAR
    float nz = dpp_mov<0x130, 0xF>(zz.x, 0.0f);
    float d0 = zz.y - zz.x;
    float d1 = zz.z - zz.y;
    float d2 = zz.w - zz.z;
    float d3 = (sub == 31) ? FAR_F : (nz - zz.w);

    float e0 = __expf(-d0 * dns.x);
    float e1 = __expf(-d1 * dns.y);
    float e2 = __expf(-d2 * dns.z);
    float e3 = __expf(-d3 * dns.w);
    float a0 = 1.0f - e0, a1 = 1.0f - e1, a2 = 1.0f - e2, a3 = 1.0f - e3;
    float f0 = e0 + EPS_F, f1 = e1 + EPS_F, f2 = e2 + EPS_F, f3 = e3 + EPS_F;

    // local prefix products, then 32-lane inclusive product scan
    float f01  = f0 * f1;
    float f012 = f01 * f2;
    float p    = f012 * f3;
    p *= dpp_mov<0x111, 0xF>(p, 1.0f);
    p *= dpp_mov<0x112, 0xF>(p, 1.0f);
    p *= dpp_mov<0x114, 0xF>(p, 1.0f);
    p *= dpp_mov<0x118, 0xF>(p, 1.0f);
    p *= dpp_mov<0x142, 0xA>(p, 1.0f);       // rows 1,3 *= preceding row total
    float Ts = dpp_mov<0x138, 0xF>(p, 1.0f); // exclusive shift (wave_shr1)
    if (sub == 0) Ts = 1.0f;                 // lane 32 received lane31's value

    float w0 = Ts * a0;
    float T1 = Ts * f0;   float w1 = T1 * a1;
    float T2 = Ts * f01;  float w2 = T2 * a2;
    float T3 = Ts * f012; float w3 = T3 * a3;

    // fa=(p0x,p0y,p0z,p1x) fb=(p1y,p1z,p2x,p2y) fc=(p2z,p3x,p3y,p3z)
    float rx = half32_reduce_add(w0 * fa.x + w1 * fa.w + w2 * fb.z + w3 * fc.y);
    float ry = half32_reduce_add(w0 * fa.y + w1 * fb.x + w2 * fb.w + w3 * fc.z);
    float rz = half32_reduce_add(w0 * fa.z + w1 * fb.y + w2 * fc.x + w3 * fc.w);
    float dd = half32_reduce_add(w0 * zz.x + w1 * zz.y + w2 * zz.z + w3 * zz.w);

    if (sub == 31) {   // lanes 31 (ray A) and 63 (ray B) hold the totals
        float* o  = out + (size_t)ray * 3;
        o[0] = rx; o[1] = ry; o[2] = rz;
        float* od = out + (size_t)n_rays * 3 + (size_t)ray * 3;
        od[0] = dd; od[1] = dd; od[2] = dd;
    }
}

// Persistent waves, 2 rays/wave/iter, depth-2 ping-pong register pipeline.
// No LDS, no barriers, no vmcnt(0) drain inside the loop: consuming stage A
// waits only on A's 5 loads (counted vmcnt) while stage B stays in flight.
__global__ __launch_bounds__(256) void volrend_kernel(
        const float* __restrict__ density,
        const float* __restrict__ feature,
        const float* __restrict__ depth,
        float* __restrict__ out, int n_rays, int iters) {
    const int lane = threadIdx.x & 63;
    const int sub  = lane & 31;
    const int h    = lane >> 5;
    const int gw   = blockIdx.x * 4 + (threadIdx.x >> 6);   // global wave id
    const int rstep = gridDim.x * 4 * 2;                    // rays per iter chip-wide

    int ray0 = gw * 2 + h;                                  // this lane's ray cursor
    size_t doff = (size_t)ray0 * N_PTS + (sub << 2);        // density/depth elem off
    size_t foff = (size_t)ray0 * (N_PTS * 3) + sub * 12;    // feature elem off
    const size_t dstep = (size_t)rstep * N_PTS;
    const size_t fstep = (size_t)rstep * (N_PTS * 3);

    // prologue: issue stage A (iter 0) and stage B (iter 1) loads back-to-back
    float4 dA = *(const float4*)(density + doff);
    float4 zA = *(const float4*)(depth   + doff);
    const float4* fpA = (const float4*)(feature + foff);
    float4 aA = fpA[0], bA = fpA[1], cA = fpA[2];

    float4 dB, zB, aB, bB, cB;
    if (iters > 1) {
        dB = *(const float4*)(density + doff + dstep);
        zB = *(const float4*)(depth   + doff + dstep);
        const float4* fpB = (const float4*)(feature + foff + fstep);
        aB = fpB[0]; bB = fpB[1]; cB = fpB[2];
    }
    doff += 2 * dstep; foff += 2 * fstep;   // prefetch cursor now at iter 2

    int ray_c = ray0;
    for (int k = 0; k < iters; k += 2) {
        // consume A (vmcnt waits only for A's loads; B outstanding)
        process_pair(dA, zA, aA, bA, cA, sub, ray_c, n_rays, out);
        if (k + 2 < iters) {                 // refill A with iter k+2
            dA = *(const float4*)(density + doff);
            zA = *(const float4*)(depth   + doff);
            const float4* fp = (const float4*)(feature + foff);
            aA = fp[0]; bA = fp[1]; cA = fp[2];
            doff += dstep; foff += fstep;
        }
        ray_c += rstep;
        if (k + 1 >= iters) break;

        // consume B (A-refill outstanding)
        process_pair(dB, zB, aB, bB, cB, sub, ray_c, n_rays, out);
        if (k + 3 < iters) {                 // refill B with iter k+3
            dB = *(const float4*)(density + doff);
            zB = *(const float4*)(depth   + doff);
            const float4* fp = (const float4*)(feature + foff);
            aB = fp[0]; bB = fp[1]; cB = fp[2];
            doff += dstep; foff += fstep;
        }
        ray_c += rstep;
    }
}

extern "C" void kernel_launch(void* const* d_in, const int* in_sizes, int n_in,
                              void* d_out, int out_size, void* d_ws, size_t ws_size,
                              hipStream_t stream) {
    const float* density = (const float*)d_in[0];
    const float* feature = (const float*)d_in[1];
    const float* depth   = (const float*)d_in[2];
    float* out = (float*)d_out;
    const int n_rays = in_sizes[0] / N_PTS;       // 65536
    int nblk8 = n_rays / 8;                       // ray-pairs per chip-sweep unit
    int grid = nblk8 < MAX_GRID ? nblk8 : MAX_GRID;
    while (grid > 1 && (nblk8 % grid)) --grid;    // keep iteration count exact
    const int iters = nblk8 / grid;               // 4 for the bench shape
    volrend_kernel<<<grid, 256, 0, stream>>>(density, feature, depth, out,
                                             n_rays, iters);
}

// Round 4
// 179.698 us; speedup vs baseline: 1.0777x; 1.0706x over previous
//
#include <hip/hip_runtime.h>

#define N_PTS 128
#define EPS_F 1e-10f
#define FAR_F 1e10f

typedef float f4 __attribute__((ext_vector_type(4)));

// DPP ctrl encodings (gfx9/CDNA):
//   ROW_SHR1=0x111 SHR2=0x112 SHR4=0x114 SHR8=0x118
//   ROW_BCAST15=0x142 ROW_BCAST31=0x143
//   WAVE_SHL1=0x130 (lane i <- i+1)   WAVE_SHR1=0x138 (lane i <- i-1)
template<int CTRL, int ROW_MASK>
__device__ __forceinline__ float dpp_mov(float src, float old) {
    union { float f; int i; } s, o, r;
    s.f = src; o.f = old;
    r.i = __builtin_amdgcn_update_dpp(o.i, s.i, CTRL, ROW_MASK, 0xF, false);
    return r.f;
}

// 32-lane (half-wave) sum; totals land in lane 31 (half A) and lane 63 (half B).
__device__ __forceinline__ float half32_reduce_add(float x) {
    x += dpp_mov<0x111, 0xF>(x, 0.0f);
    x += dpp_mov<0x112, 0xF>(x, 0.0f);
    x += dpp_mov<0x114, 0xF>(x, 0.0f);
    x += dpp_mov<0x118, 0xF>(x, 0.0f);
    x += dpp_mov<0x142, 0xA>(x, 0.0f);  // row1 += lane15 tot, row3 += lane47 tot
    return x;
}

// One wave = 2 rays (lanes 0-31 ray A, lanes 32-63 ray B); lane owns points
// 4*sub .. 4*sub+3. One-shot waves (equal-best structure across R0-R3).
// All input loads NON-TEMPORAL: streams are read-once within a dispatch, so
// skip L1 allocation / free line-fill resources (theory: per-CU fill-pool cap).
__global__ __launch_bounds__(256) void volrend_kernel(
        const float* __restrict__ density,
        const float* __restrict__ feature,
        const float* __restrict__ depth,
        float* __restrict__ out, int n_rays) {
    const int lane = threadIdx.x & 63;
    const int sub  = lane & 31;          // lane within the 32-lane half
    const int h    = lane >> 5;          // which ray of the pair
    const int ray  = blockIdx.x * 8 + (threadIdx.x >> 6) * 2 + h;
    if (ray >= n_rays) return;

    const size_t doff = (size_t)ray * N_PTS + (sub << 2);
    const f4 dns = __builtin_nontemporal_load((const f4*)(density + doff));
    const f4 zz  = __builtin_nontemporal_load((const f4*)(depth   + doff));
    const f4* fp = (const f4*)(feature + (size_t)ray * (N_PTS * 3) + sub * 12);
    const f4 fa = __builtin_nontemporal_load(fp + 0);  // p0x p0y p0z p1x
    const f4 fb = __builtin_nontemporal_load(fp + 1);  // p1y p1z p2x p2y
    const f4 fc = __builtin_nontemporal_load(fp + 2);  // p2z p3x p3y p3z

    // deltas: next lane's z0 via wave_shl1; lanes 31/63 overridden with FAR
    float nz = dpp_mov<0x130, 0xF>(zz.x, 0.0f);
    float d0 = zz.y - zz.x;
    float d1 = zz.z - zz.y;
    float d2 = zz.w - zz.z;
    float d3 = (sub == 31) ? FAR_F : (nz - zz.w);

    float e0 = __expf(-d0 * dns.x);
    float e1 = __expf(-d1 * dns.y);
    float e2 = __expf(-d2 * dns.z);
    float e3 = __expf(-d3 * dns.w);
    float a0 = 1.0f - e0, a1 = 1.0f - e1, a2 = 1.0f - e2, a3 = 1.0f - e3;
    float f0 = e0 + EPS_F, f1 = e1 + EPS_F, f2 = e2 + EPS_F, f3 = e3 + EPS_F;

    // local prefix products, then 32-lane inclusive product scan
    float f01  = f0 * f1;
    float f012 = f01 * f2;
    float p    = f012 * f3;
    p *= dpp_mov<0x111, 0xF>(p, 1.0f);
    p *= dpp_mov<0x112, 0xF>(p, 1.0f);
    p *= dpp_mov<0x114, 0xF>(p, 1.0f);
    p *= dpp_mov<0x118, 0xF>(p, 1.0f);
    p *= dpp_mov<0x142, 0xA>(p, 1.0f);       // rows 1,3 *= preceding row total
    float Ts = dpp_mov<0x138, 0xF>(p, 1.0f); // exclusive shift (wave_shr1)
    if (sub == 0) Ts = 1.0f;                 // lane 32 received lane31's value

    float w0 = Ts * a0;
    float T1 = Ts * f0;   float w1 = T1 * a1;
    float T2 = Ts * f01;  float w2 = T2 * a2;
    float T3 = Ts * f012; float w3 = T3 * a3;

    float rx = half32_reduce_add(w0 * fa.x + w1 * fa.w + w2 * fb.z + w3 * fc.y);
    float ry = half32_reduce_add(w0 * fa.y + w1 * fb.x + w2 * fb.w + w3 * fc.z);
    float rz = half32_reduce_add(w0 * fa.z + w1 * fb.y + w2 * fc.x + w3 * fc.w);
    float dd = half32_reduce_add(w0 * zz.x + w1 * zz.y + w2 * zz.z + w3 * zz.w);

    if (sub == 31) {   // lanes 31 (ray A) and 63 (ray B) hold the totals
        float* o  = out + (size_t)ray * 3;
        o[0] = rx; o[1] = ry; o[2] = rz;
        float* od = out + (size_t)n_rays * 3 + (size_t)ray * 3;
        od[0] = dd; od[1] = dd; od[2] = dd;
    }
}

extern "C" void kernel_launch(void* const* d_in, const int* in_sizes, int n_in,
                              void* d_out, int out_size, void* d_ws, size_t ws_size,
                              hipStream_t stream) {
    const float* density = (const float*)d_in[0];
    const float* feature = (const float*)d_in[1];
    const float* depth   = (const float*)d_in[2];
    float* out = (float*)d_out;
    const int n_rays = in_sizes[0] / N_PTS;   // 65536
    const int blocks = (n_rays + 7) / 8;      // 8 rays per 256-thread block
    volrend_kernel<<<blocks, 256, 0, stream>>>(density, feature, depth, out, n_rays);
}